// Round 4
// baseline (3434.819 us; speedup 1.0000x reference)
//
#include <hip/hip_runtime.h>

// MPNN encoder, MI355X — round 4.
// Round-3 rocprof: edge_kernel VALUBusy 59%, Occupancy 40% (37.9KB LDS -> 4
// blocks/CU). Fixes: (1) 2-phase LDS reduce, 19.4KB -> 8 blocks/CU;
// (2) node kernel native v_exp/v_rcp instead of libm expf/tanhf;
// (3) node kernel LDS scratch removed (global round-trip + vmcnt(0)).
//
//  - edge_feat / GRU_e dead w.r.t. output -> skipped.
//  - layer1 factorized: h1 = relu(u[s] + v[d] + W1p*dpos + b1).
//  - segment_sum: counting sort by source + in-LDS segmented reduce,
//    boundary-only f32 atomics.

#define NN      50000
#define NE      800000
#define NE2     (2 * NE)
#define NCLS    16

// ---------------- prep: build combined GRU gate matrix ----------------
__global__ __launch_bounds__(256) void prep_kernel(
    const float* __restrict__ Wih, const float* __restrict__ Whh,
    const float* __restrict__ bih, const float* __restrict__ bhh,
    float* __restrict__ Wg, float* __restrict__ bg)
{
    int idx = blockIdx.x * 256 + threadIdx.x;
    if (idx < 8192) {
        int o = idx >> 6, k = idx & 63;
        float val;
        if (o < 64) {
            val = (k < 32) ? Wih[o * 32 + k] : Whh[o * 32 + (k - 32)];
        } else if (o < 96) {
            val = (k < 32) ? Wih[o * 32 + k] : 0.0f;
        } else {
            val = (k >= 32) ? Whh[(o - 32) * 32 + (k - 32)] : 0.0f;
        }
        Wg[idx] = val;
    } else if (idx < 8320) {
        int i = idx - 8192;
        float val;
        if (i < 64)       val = bih[i] + bhh[i];
        else if (i < 96)  val = bih[i];
        else              val = bhh[i - 32];
        bg[i] = val;
    }
}

// ---------------- sort: rank-histogram, scan, scatter ----------------
__global__ __launch_bounds__(256) void hist_rank_kernel(
    const int* __restrict__ e0, const int* __restrict__ e1,
    int* __restrict__ deg, int* __restrict__ rank)
{
    int e = blockIdx.x * 256 + threadIdx.x;   // grid exactly NE2/256
    int s = (e < NE) ? e0[e] : e1[e - NE];
    rank[e] = atomicAdd(&deg[s], 1);          // rank store is coalesced
}

__global__ __launch_bounds__(1024) void scan_kernel(
    const int* __restrict__ deg, int* __restrict__ rowptr)
{
    __shared__ int part[1024];
    int tid = threadIdx.x;
    int beg = tid * 49;                        // 1024*49 = 50176 >= NN
    int sum = 0;
#pragma unroll 7
    for (int i = 0; i < 49; ++i) {
        int idx = beg + i;
        if (idx < NN) sum += deg[idx];
    }
    part[tid] = sum;
    __syncthreads();
    for (int off = 1; off < 1024; off <<= 1) {
        int t = (tid >= off) ? part[tid - off] : 0;
        __syncthreads();
        part[tid] += t;
        __syncthreads();
    }
    int run = part[tid] - sum;                 // exclusive prefix
#pragma unroll 7
    for (int i = 0; i < 49; ++i) {
        int idx = beg + i;
        if (idx < NN) { rowptr[idx] = run; run += deg[idx]; }
    }
    if (tid == 1023) rowptr[NN] = run;         // == NE2
}

__global__ __launch_bounds__(256) void scatter_kernel(
    const int* __restrict__ e0, const int* __restrict__ e1,
    const int* __restrict__ rowptr, const int* __restrict__ rank,
    int2* __restrict__ sd)
{
    int e = blockIdx.x * 256 + threadIdx.x;   // grid exactly NE2/256
    int s, d;
    if (e < NE) { s = e0[e]; d = e1[e]; }
    else        { s = e1[e - NE]; d = e0[e - NE]; }
    int p = rowptr[s] + rank[e];
    sd[p] = make_int2(s, d);                  // single scattered 8B store
}

// ---------------- u,v projection ----------------
__device__ __forceinline__ void proj_uv(const float nn[32], int n,
                                        const float* __restrict__ W1,
                                        float* __restrict__ u, float* __restrict__ v)
{
    for (int j = 0; j < 32; ++j) {            // rolled: W1 addrs uniform -> s_load
        float su = 0.0f, sv = 0.0f;
#pragma unroll
        for (int k = 0; k < 32; ++k) {
            su = fmaf(W1[j * 67 + k],      nn[k], su);
            sv = fmaf(W1[j * 67 + 32 + k], nn[k], sv);
        }
        u[(size_t)n * 32 + j] = su;
        v[(size_t)n * 32 + j] = sv;
    }
}

// ---------------- init: node = classes@W_in.T + b_in; emit u,v; zero acc ------
__global__ __launch_bounds__(256) void init_kernel(
    const float* __restrict__ classes, const float* __restrict__ W_in,
    const float* __restrict__ b_in, const float* __restrict__ W1,
    float* __restrict__ node, float* __restrict__ u, float* __restrict__ v,
    float* __restrict__ acc)
{
    int n = blockIdx.x * 256 + threadIdx.x;
    if (n >= NN) return;

    float cls[16];
    const float4* cr = reinterpret_cast<const float4*>(classes + (size_t)n * NCLS);
#pragma unroll
    for (int q = 0; q < 4; ++q) {
        float4 c4 = cr[q];
        cls[q * 4 + 0] = c4.x; cls[q * 4 + 1] = c4.y;
        cls[q * 4 + 2] = c4.z; cls[q * 4 + 3] = c4.w;
    }

    float nn[32];
#pragma unroll
    for (int j = 0; j < 32; ++j) {
        float t = b_in[j];
#pragma unroll
        for (int k = 0; k < 16; ++k) t = fmaf(W_in[j * 16 + k], cls[k], t);
        nn[j] = t;
        node[(size_t)n * 32 + j] = t;
    }

    float4 z4 = make_float4(0.f, 0.f, 0.f, 0.f);
    float4* aw = reinterpret_cast<float4*>(acc + (size_t)n * 32);
#pragma unroll
    for (int q = 0; q < 8; ++q) aw[q] = z4;

    proj_uv(nn, n, W1, u, v);
}

// ---------------- fused edge kernel: MLP -> 2-phase LDS segmented reduce -----
#define H1STEP(j, uu, vv)                                                            \
    {                                                                                \
        float pre = (uu) + (vv) + dx * W1[(j) * 67 + 64] + dy * W1[(j) * 67 + 65]    \
                    + dz * W1[(j) * 67 + 66] + b1[j];                                \
        h1[j] = fmaxf(pre, 0.0f);                                                    \
    }

__global__ __launch_bounds__(256, 8) void edge_kernel(
    const int2* __restrict__ sd, const float* __restrict__ pos,
    const float* __restrict__ u, const float* __restrict__ v,
    const float* __restrict__ W1, const float* __restrict__ b1,
    const float* __restrict__ W2, const float* __restrict__ b2,
    const float* __restrict__ W3, const float* __restrict__ b3,
    float* __restrict__ acc)
{
    // 128-row tile: 128*36*4 + 256*4 = 19.4KB -> 8 blocks/CU (full wave cap).
    // Stride 36 floats: ds_write_b128 and scalar column reads conflict-free
    // (round-3 measured SQ_LDS_BANK_CONFLICT = 0).
    __shared__ float mld[128][36];
    __shared__ int   slds[256];

    int tid = threadIdx.x;
    int e = blockIdx.x * 256 + tid;           // grid exactly NE2/256
    int2 p = sd[e];
    int s = p.x, d = p.y;
    slds[tid] = s;

    float dx = pos[d * 3 + 0] - pos[s * 3 + 0];
    float dy = pos[d * 3 + 1] - pos[s * 3 + 1];
    float dz = pos[d * 3 + 2] - pos[s * 3 + 2];

    const float4* ur = reinterpret_cast<const float4*>(u + (size_t)s * 32);
    const float4* vr = reinterpret_cast<const float4*>(v + (size_t)d * 32);

    float h1[32];
#pragma unroll
    for (int q = 0; q < 8; ++q) {
        float4 uq = ur[q];
        float4 vq = vr[q];
        H1STEP(q * 4 + 0, uq.x, vq.x);
        H1STEP(q * 4 + 1, uq.y, vq.y);
        H1STEP(q * 4 + 2, uq.z, vq.z);
        H1STEP(q * 4 + 3, uq.w, vq.w);
    }

    float h2[32];
#pragma unroll
    for (int o = 0; o < 32; ++o) {
        float t = b2[o];
#pragma unroll
        for (int k = 0; k < 32; ++k) t = fmaf(W2[o * 32 + k], h1[k], t);
        h2[o] = fmaxf(t, 0.0f);
    }

    float m[32];                               // statically indexed -> registers
#pragma unroll
    for (int o = 0; o < 32; ++o) {
        float t = b3[o];
#pragma unroll
        for (int k = 0; k < 32; ++k) t = fmaf(W3[o * 32 + k], h2[k], t);
        m[o] = t;
    }

    int c = tid & 31, g = tid >> 5;            // 32 cols x 8 row-groups

    // ---- phase 1: rows 0..127 ----
    if (tid < 128) {
#pragma unroll
        for (int q = 0; q < 8; ++q)
            *reinterpret_cast<float4*>(&mld[tid][q * 4]) =
                make_float4(m[q * 4], m[q * 4 + 1], m[q * 4 + 2], m[q * 4 + 3]);
    }
    __syncthreads();
    {
        int base = g * 16;
        int scur = slds[base];
        float sum = 0.0f;
        for (int r = 0; r < 16; ++r) {
            int row = base + r;
            int sr = slds[row];
            if (sr != scur) {
                unsafeAtomicAdd(&acc[(size_t)scur * 32 + c], sum);
                sum = 0.0f;
                scur = sr;
            }
            sum += mld[row][c];
        }
        unsafeAtomicAdd(&acc[(size_t)scur * 32 + c], sum);
    }
    __syncthreads();

    // ---- phase 2: rows 128..255 ----
    if (tid >= 128) {
#pragma unroll
        for (int q = 0; q < 8; ++q)
            *reinterpret_cast<float4*>(&mld[tid - 128][q * 4]) =
                make_float4(m[q * 4], m[q * 4 + 1], m[q * 4 + 2], m[q * 4 + 3]);
    }
    __syncthreads();
    {
        int base = 128 + g * 16;
        int scur = slds[base];
        float sum = 0.0f;
        for (int r = 0; r < 16; ++r) {
            int row = base + r;
            int sr = slds[row];
            if (sr != scur) {
                unsafeAtomicAdd(&acc[(size_t)scur * 32 + c], sum);
                sum = 0.0f;
                scur = sr;
            }
            sum += mld[row - 128][c];
        }
        unsafeAtomicAdd(&acc[(size_t)scur * 32 + c], sum);
    }
}

// ---------------- node kernel: GRU (native exp/rcp) + next-iter u,v ----------
__global__ __launch_bounds__(256) void node_kernel(
    float* __restrict__ node, float* __restrict__ acc,
    const float* __restrict__ Wg, const float* __restrict__ bg,
    const float* __restrict__ W1,
    float* __restrict__ u, float* __restrict__ v, int last)
{
    int n = blockIdx.x * 256 + threadIdx.x;
    if (n >= NN) return;

    float a[32], h[32];
    const float4* ar = reinterpret_cast<const float4*>(acc + (size_t)n * 32);
    const float4* hr = reinterpret_cast<const float4*>(node + (size_t)n * 32);
#pragma unroll
    for (int q = 0; q < 8; ++q) {
        float4 a4 = ar[q];
        a[q * 4 + 0] = a4.x; a[q * 4 + 1] = a4.y; a[q * 4 + 2] = a4.z; a[q * 4 + 3] = a4.w;
        float4 h4 = hr[q];
        h[q * 4 + 0] = h4.x; h[q * 4 + 1] = h4.y; h[q * 4 + 2] = h4.z; h[q * 4 + 3] = h4.w;
    }

    // re-zero acc row for the next edge pass
    float4 z4 = make_float4(0.f, 0.f, 0.f, 0.f);
    float4* aw = reinterpret_cast<float4*>(acc + (size_t)n * 32);
#pragma unroll
    for (int q = 0; q < 8; ++q) aw[q] = z4;

    for (int j = 0; j < 32; ++j) {   // rolled: Wg addrs uniform -> s_load
        float gr = bg[j], gz = bg[32 + j], gin = bg[64 + j], ghn = bg[96 + j];
#pragma unroll
        for (int k = 0; k < 32; ++k) {
            gr  = fmaf(Wg[j * 64 + k],             a[k], gr);
            gr  = fmaf(Wg[j * 64 + 32 + k],        h[k], gr);
            gz  = fmaf(Wg[(32 + j) * 64 + k],      a[k], gz);
            gz  = fmaf(Wg[(32 + j) * 64 + 32 + k], h[k], gz);
            gin = fmaf(Wg[(64 + j) * 64 + k],      a[k], gin);
            ghn = fmaf(Wg[(96 + j) * 64 + 32 + k], h[k], ghn);
        }
        // native transcendentals: v_exp_f32 + v_rcp_f32 (~2^-21 rel err,
        // far below the 2^-8 passing absmax).
        float r  = __builtin_amdgcn_rcpf(1.0f + __expf(-gr));
        float zz = __builtin_amdgcn_rcpf(1.0f + __expf(-gz));
        float pre = fmaf(r, ghn, gin);
        float nj  = 1.0f - 2.0f * __builtin_amdgcn_rcpf(1.0f + __expf(2.0f * pre));
        float out = fmaf(zz, h[j] - nj, nj);      // (1-z)*n + z*h
        node[(size_t)n * 32 + j] = out;
    }

    if (!last) {
        // stores above are same-thread; drain vmcnt then reload row via L1.
        asm volatile("s_waitcnt vmcnt(0)" ::: "memory");
        float nn[32];
        const float4* nr = reinterpret_cast<const float4*>(node + (size_t)n * 32);
#pragma unroll
        for (int q = 0; q < 8; ++q) {
            float4 n4 = nr[q];
            nn[q * 4 + 0] = n4.x; nn[q * 4 + 1] = n4.y;
            nn[q * 4 + 2] = n4.z; nn[q * 4 + 3] = n4.w;
        }
        proj_uv(nn, n, W1, u, v);
    }
}

// ---------------- launch ----------------
extern "C" void kernel_launch(void* const* d_in, const int* in_sizes, int n_in,
                              void* d_out, int out_size, void* d_ws, size_t ws_size,
                              hipStream_t stream)
{
    const float* pos     = (const float*)d_in[0];
    const float* classes = (const float*)d_in[1];
    const int*   edges   = (const int*)d_in[2];
    const float* W_in = (const float*)d_in[4];
    const float* b_in = (const float*)d_in[5];
    const float* W1   = (const float*)d_in[6];
    const float* b1   = (const float*)d_in[7];
    const float* W2   = (const float*)d_in[8];
    const float* b2   = (const float*)d_in[9];
    const float* W3   = (const float*)d_in[10];
    const float* b3   = (const float*)d_in[11];
    const float* Wih_n = (const float*)d_in[12];
    const float* Whh_n = (const float*)d_in[13];
    const float* bih_n = (const float*)d_in[14];
    const float* bhh_n = (const float*)d_in[15];
    // d_in[16..19]: edge-GRU params — dead w.r.t. the output.

    float* node = (float*)d_out;                  // [NN][32] persistent

    float* ws  = (float*)d_ws;
    float* u   = ws;                              // [NN][32]
    float* v   = u + (size_t)NN * 32;             // [NN][32]
    float* acc = v + (size_t)NN * 32;             // [NN][32]
    float* Wg  = acc + (size_t)NN * 32;           // [128][64]
    float* bg  = Wg + 128 * 64;                   // [128]
    int* deg    = (int*)(bg + 128);               // [NN]
    int* rank   = deg + NN;                       // [NE2]
    int* rowptr = rank + NE2;                     // [NN+1]
    uintptr_t sp = (uintptr_t)(rowptr + NN + 1);
    sp = (sp + 255) & ~(uintptr_t)255;
    int2* sd = (int2*)sp;                         // [NE2] packed (s,d)

    const int* e0 = edges;
    const int* e1 = edges + NE;

    prep_kernel<<<33, 256, 0, stream>>>(Wih_n, Whh_n, bih_n, bhh_n, Wg, bg);
    hipMemsetAsync(deg, 0, (size_t)NN * sizeof(int), stream);
    hist_rank_kernel<<<NE2 / 256, 256, 0, stream>>>(e0, e1, deg, rank);
    scan_kernel<<<1, 1024, 0, stream>>>(deg, rowptr);
    scatter_kernel<<<NE2 / 256, 256, 0, stream>>>(e0, e1, rowptr, rank, sd);
    init_kernel<<<(NN + 255) / 256, 256, 0, stream>>>(classes, W_in, b_in, W1,
                                                      node, u, v, acc);
    for (int it = 0; it < 6; ++it) {
        edge_kernel<<<NE2 / 256, 256, 0, stream>>>(sd, pos, u, v,
                                                   W1, b1, W2, b2, W3, b3, acc);
        node_kernel<<<(NN + 255) / 256, 256, 0, stream>>>(node, acc, Wg, bg, W1,
                                                          u, v, it == 5);
    }
}

// Round 5
// 1405.405 us; speedup vs baseline: 2.4440x; 2.4440x over previous
//
#include <hip/hip_runtime.h>

// MPNN encoder, MI355X — round 5.
// Round-4 regression diagnosed: __launch_bounds__(256,8) capped VGPR at 32,
// spilling m[32]/h1/h2 to scratch (FETCH 67MB->1.12GB, WRITE 12.5->758MB,
// VALUBusy 19%). Fix: (256,4) -> 128-VGPR budget, no spill, occupancy
// VGPR-capped ~87% instead of LDS-capped 50%. Everything else from round 4
// kept (2-phase 19.4KB LDS reduce; node kernel native exp/rcp, no LDS).
//
//  - edge_feat / GRU_e dead w.r.t. output -> skipped.
//  - layer1 factorized: h1 = relu(u[s] + v[d] + W1p*dpos + b1).
//  - segment_sum: counting sort by source + in-LDS segmented reduce,
//    boundary-only f32 atomics.

#define NN      50000
#define NE      800000
#define NE2     (2 * NE)
#define NCLS    16

// ---------------- prep: build combined GRU gate matrix ----------------
__global__ __launch_bounds__(256) void prep_kernel(
    const float* __restrict__ Wih, const float* __restrict__ Whh,
    const float* __restrict__ bih, const float* __restrict__ bhh,
    float* __restrict__ Wg, float* __restrict__ bg)
{
    int idx = blockIdx.x * 256 + threadIdx.x;
    if (idx < 8192) {
        int o = idx >> 6, k = idx & 63;
        float val;
        if (o < 64) {
            val = (k < 32) ? Wih[o * 32 + k] : Whh[o * 32 + (k - 32)];
        } else if (o < 96) {
            val = (k < 32) ? Wih[o * 32 + k] : 0.0f;
        } else {
            val = (k >= 32) ? Whh[(o - 32) * 32 + (k - 32)] : 0.0f;
        }
        Wg[idx] = val;
    } else if (idx < 8320) {
        int i = idx - 8192;
        float val;
        if (i < 64)       val = bih[i] + bhh[i];
        else if (i < 96)  val = bih[i];
        else              val = bhh[i - 32];
        bg[i] = val;
    }
}

// ---------------- sort: rank-histogram, scan, scatter ----------------
__global__ __launch_bounds__(256) void hist_rank_kernel(
    const int* __restrict__ e0, const int* __restrict__ e1,
    int* __restrict__ deg, int* __restrict__ rank)
{
    int e = blockIdx.x * 256 + threadIdx.x;   // grid exactly NE2/256
    int s = (e < NE) ? e0[e] : e1[e - NE];
    rank[e] = atomicAdd(&deg[s], 1);          // rank store is coalesced
}

__global__ __launch_bounds__(1024) void scan_kernel(
    const int* __restrict__ deg, int* __restrict__ rowptr)
{
    __shared__ int part[1024];
    int tid = threadIdx.x;
    int beg = tid * 49;                        // 1024*49 = 50176 >= NN
    int sum = 0;
#pragma unroll 7
    for (int i = 0; i < 49; ++i) {
        int idx = beg + i;
        if (idx < NN) sum += deg[idx];
    }
    part[tid] = sum;
    __syncthreads();
    for (int off = 1; off < 1024; off <<= 1) {
        int t = (tid >= off) ? part[tid - off] : 0;
        __syncthreads();
        part[tid] += t;
        __syncthreads();
    }
    int run = part[tid] - sum;                 // exclusive prefix
#pragma unroll 7
    for (int i = 0; i < 49; ++i) {
        int idx = beg + i;
        if (idx < NN) { rowptr[idx] = run; run += deg[idx]; }
    }
    if (tid == 1023) rowptr[NN] = run;         // == NE2
}

__global__ __launch_bounds__(256) void scatter_kernel(
    const int* __restrict__ e0, const int* __restrict__ e1,
    const int* __restrict__ rowptr, const int* __restrict__ rank,
    int2* __restrict__ sd)
{
    int e = blockIdx.x * 256 + threadIdx.x;   // grid exactly NE2/256
    int s, d;
    if (e < NE) { s = e0[e]; d = e1[e]; }
    else        { s = e1[e - NE]; d = e0[e - NE]; }
    int p = rowptr[s] + rank[e];
    sd[p] = make_int2(s, d);                  // single scattered 8B store
}

// ---------------- u,v projection ----------------
__device__ __forceinline__ void proj_uv(const float nn[32], int n,
                                        const float* __restrict__ W1,
                                        float* __restrict__ u, float* __restrict__ v)
{
    for (int j = 0; j < 32; ++j) {            // rolled: W1 addrs uniform -> s_load
        float su = 0.0f, sv = 0.0f;
#pragma unroll
        for (int k = 0; k < 32; ++k) {
            su = fmaf(W1[j * 67 + k],      nn[k], su);
            sv = fmaf(W1[j * 67 + 32 + k], nn[k], sv);
        }
        u[(size_t)n * 32 + j] = su;
        v[(size_t)n * 32 + j] = sv;
    }
}

// ---------------- init: node = classes@W_in.T + b_in; emit u,v; zero acc ------
__global__ __launch_bounds__(256) void init_kernel(
    const float* __restrict__ classes, const float* __restrict__ W_in,
    const float* __restrict__ b_in, const float* __restrict__ W1,
    float* __restrict__ node, float* __restrict__ u, float* __restrict__ v,
    float* __restrict__ acc)
{
    int n = blockIdx.x * 256 + threadIdx.x;
    if (n >= NN) return;

    float cls[16];
    const float4* cr = reinterpret_cast<const float4*>(classes + (size_t)n * NCLS);
#pragma unroll
    for (int q = 0; q < 4; ++q) {
        float4 c4 = cr[q];
        cls[q * 4 + 0] = c4.x; cls[q * 4 + 1] = c4.y;
        cls[q * 4 + 2] = c4.z; cls[q * 4 + 3] = c4.w;
    }

    float nn[32];
#pragma unroll
    for (int j = 0; j < 32; ++j) {
        float t = b_in[j];
#pragma unroll
        for (int k = 0; k < 16; ++k) t = fmaf(W_in[j * 16 + k], cls[k], t);
        nn[j] = t;
        node[(size_t)n * 32 + j] = t;
    }

    float4 z4 = make_float4(0.f, 0.f, 0.f, 0.f);
    float4* aw = reinterpret_cast<float4*>(acc + (size_t)n * 32);
#pragma unroll
    for (int q = 0; q < 8; ++q) aw[q] = z4;

    proj_uv(nn, n, W1, u, v);
}

// ---------------- fused edge kernel: MLP -> 2-phase LDS segmented reduce -----
#define H1STEP(j, uu, vv)                                                            \
    {                                                                                \
        float pre = (uu) + (vv) + dx * W1[(j) * 67 + 64] + dy * W1[(j) * 67 + 65]    \
                    + dz * W1[(j) * 67 + 66] + b1[j];                                \
        h1[j] = fmaxf(pre, 0.0f);                                                    \
    }

__global__ __launch_bounds__(256, 4) void edge_kernel(
    const int2* __restrict__ sd, const float* __restrict__ pos,
    const float* __restrict__ u, const float* __restrict__ v,
    const float* __restrict__ W1, const float* __restrict__ b1,
    const float* __restrict__ W2, const float* __restrict__ b2,
    const float* __restrict__ W3, const float* __restrict__ b3,
    float* __restrict__ acc)
{
    // 128-row tile: 128*36*4 + 256*4 = 19.4KB. With (256,4): 128-VGPR budget
    // (no spill — round-4's (256,8) forced 32 VGPR and spilled m[32] to
    // scratch, FETCH 67MB->1.12GB). Occupancy becomes VGPR-capped ~7w/SIMD.
    __shared__ float mld[128][36];
    __shared__ int   slds[256];

    int tid = threadIdx.x;
    int e = blockIdx.x * 256 + tid;           // grid exactly NE2/256
    int2 p = sd[e];
    int s = p.x, d = p.y;
    slds[tid] = s;

    float dx = pos[d * 3 + 0] - pos[s * 3 + 0];
    float dy = pos[d * 3 + 1] - pos[s * 3 + 1];
    float dz = pos[d * 3 + 2] - pos[s * 3 + 2];

    const float4* ur = reinterpret_cast<const float4*>(u + (size_t)s * 32);
    const float4* vr = reinterpret_cast<const float4*>(v + (size_t)d * 32);

    float h1[32];
#pragma unroll
    for (int q = 0; q < 8; ++q) {
        float4 uq = ur[q];
        float4 vq = vr[q];
        H1STEP(q * 4 + 0, uq.x, vq.x);
        H1STEP(q * 4 + 1, uq.y, vq.y);
        H1STEP(q * 4 + 2, uq.z, vq.z);
        H1STEP(q * 4 + 3, uq.w, vq.w);
    }

    float h2[32];
#pragma unroll
    for (int o = 0; o < 32; ++o) {
        float t = b2[o];
#pragma unroll
        for (int k = 0; k < 32; ++k) t = fmaf(W2[o * 32 + k], h1[k], t);
        h2[o] = fmaxf(t, 0.0f);
    }

    float m[32];                               // statically indexed -> registers
#pragma unroll
    for (int o = 0; o < 32; ++o) {
        float t = b3[o];
#pragma unroll
        for (int k = 0; k < 32; ++k) t = fmaf(W3[o * 32 + k], h2[k], t);
        m[o] = t;
    }

    int c = tid & 31, g = tid >> 5;            // 32 cols x 8 row-groups

    // ---- phase 1: rows 0..127 ----
    if (tid < 128) {
#pragma unroll
        for (int q = 0; q < 8; ++q)
            *reinterpret_cast<float4*>(&mld[tid][q * 4]) =
                make_float4(m[q * 4], m[q * 4 + 1], m[q * 4 + 2], m[q * 4 + 3]);
    }
    __syncthreads();
    {
        int base = g * 16;
        int scur = slds[base];
        float sum = 0.0f;
        for (int r = 0; r < 16; ++r) {
            int row = base + r;
            int sr = slds[row];
            if (sr != scur) {
                unsafeAtomicAdd(&acc[(size_t)scur * 32 + c], sum);
                sum = 0.0f;
                scur = sr;
            }
            sum += mld[row][c];
        }
        unsafeAtomicAdd(&acc[(size_t)scur * 32 + c], sum);
    }
    __syncthreads();

    // ---- phase 2: rows 128..255 ----
    if (tid >= 128) {
#pragma unroll
        for (int q = 0; q < 8; ++q)
            *reinterpret_cast<float4*>(&mld[tid - 128][q * 4]) =
                make_float4(m[q * 4], m[q * 4 + 1], m[q * 4 + 2], m[q * 4 + 3]);
    }
    __syncthreads();
    {
        int base = 128 + g * 16;
        int scur = slds[base];
        float sum = 0.0f;
        for (int r = 0; r < 16; ++r) {
            int row = base + r;
            int sr = slds[row];
            if (sr != scur) {
                unsafeAtomicAdd(&acc[(size_t)scur * 32 + c], sum);
                sum = 0.0f;
                scur = sr;
            }
            sum += mld[row - 128][c];
        }
        unsafeAtomicAdd(&acc[(size_t)scur * 32 + c], sum);
    }
}

// ---------------- node kernel: GRU (native exp/rcp) + next-iter u,v ----------
__global__ __launch_bounds__(256) void node_kernel(
    float* __restrict__ node, float* __restrict__ acc,
    const float* __restrict__ Wg, const float* __restrict__ bg,
    const float* __restrict__ W1,
    float* __restrict__ u, float* __restrict__ v, int last)
{
    int n = blockIdx.x * 256 + threadIdx.x;
    if (n >= NN) return;

    float a[32], h[32];
    const float4* ar = reinterpret_cast<const float4*>(acc + (size_t)n * 32);
    const float4* hr = reinterpret_cast<const float4*>(node + (size_t)n * 32);
#pragma unroll
    for (int q = 0; q < 8; ++q) {
        float4 a4 = ar[q];
        a[q * 4 + 0] = a4.x; a[q * 4 + 1] = a4.y; a[q * 4 + 2] = a4.z; a[q * 4 + 3] = a4.w;
        float4 h4 = hr[q];
        h[q * 4 + 0] = h4.x; h[q * 4 + 1] = h4.y; h[q * 4 + 2] = h4.z; h[q * 4 + 3] = h4.w;
    }

    // re-zero acc row for the next edge pass
    float4 z4 = make_float4(0.f, 0.f, 0.f, 0.f);
    float4* aw = reinterpret_cast<float4*>(acc + (size_t)n * 32);
#pragma unroll
    for (int q = 0; q < 8; ++q) aw[q] = z4;

    for (int j = 0; j < 32; ++j) {   // rolled: Wg addrs uniform -> s_load
        float gr = bg[j], gz = bg[32 + j], gin = bg[64 + j], ghn = bg[96 + j];
#pragma unroll
        for (int k = 0; k < 32; ++k) {
            gr  = fmaf(Wg[j * 64 + k],             a[k], gr);
            gr  = fmaf(Wg[j * 64 + 32 + k],        h[k], gr);
            gz  = fmaf(Wg[(32 + j) * 64 + k],      a[k], gz);
            gz  = fmaf(Wg[(32 + j) * 64 + 32 + k], h[k], gz);
            gin = fmaf(Wg[(64 + j) * 64 + k],      a[k], gin);
            ghn = fmaf(Wg[(96 + j) * 64 + 32 + k], h[k], ghn);
        }
        // native transcendentals: v_exp_f32 + v_rcp_f32 (~2^-21 rel err,
        // far below the 2^-8 passing absmax).
        float r  = __builtin_amdgcn_rcpf(1.0f + __expf(-gr));
        float zz = __builtin_amdgcn_rcpf(1.0f + __expf(-gz));
        float pre = fmaf(r, ghn, gin);
        float nj  = 1.0f - 2.0f * __builtin_amdgcn_rcpf(1.0f + __expf(2.0f * pre));
        float out = fmaf(zz, h[j] - nj, nj);      // (1-z)*n + z*h
        node[(size_t)n * 32 + j] = out;
    }

    if (!last) {
        // stores above are same-thread; drain vmcnt then reload row via L1.
        asm volatile("s_waitcnt vmcnt(0)" ::: "memory");
        float nn[32];
        const float4* nr = reinterpret_cast<const float4*>(node + (size_t)n * 32);
#pragma unroll
        for (int q = 0; q < 8; ++q) {
            float4 n4 = nr[q];
            nn[q * 4 + 0] = n4.x; nn[q * 4 + 1] = n4.y;
            nn[q * 4 + 2] = n4.z; nn[q * 4 + 3] = n4.w;
        }
        proj_uv(nn, n, W1, u, v);
    }
}

// ---------------- launch ----------------
extern "C" void kernel_launch(void* const* d_in, const int* in_sizes, int n_in,
                              void* d_out, int out_size, void* d_ws, size_t ws_size,
                              hipStream_t stream)
{
    const float* pos     = (const float*)d_in[0];
    const float* classes = (const float*)d_in[1];
    const int*   edges   = (const int*)d_in[2];
    const float* W_in = (const float*)d_in[4];
    const float* b_in = (const float*)d_in[5];
    const float* W1   = (const float*)d_in[6];
    const float* b1   = (const float*)d_in[7];
    const float* W2   = (const float*)d_in[8];
    const float* b2   = (const float*)d_in[9];
    const float* W3   = (const float*)d_in[10];
    const float* b3   = (const float*)d_in[11];
    const float* Wih_n = (const float*)d_in[12];
    const float* Whh_n = (const float*)d_in[13];
    const float* bih_n = (const float*)d_in[14];
    const float* bhh_n = (const float*)d_in[15];
    // d_in[16..19]: edge-GRU params — dead w.r.t. the output.

    float* node = (float*)d_out;                  // [NN][32] persistent

    float* ws  = (float*)d_ws;
    float* u   = ws;                              // [NN][32]
    float* v   = u + (size_t)NN * 32;             // [NN][32]
    float* acc = v + (size_t)NN * 32;             // [NN][32]
    float* Wg  = acc + (size_t)NN * 32;           // [128][64]
    float* bg  = Wg + 128 * 64;                   // [128]
    int* deg    = (int*)(bg + 128);               // [NN]
    int* rank   = deg + NN;                       // [NE2]
    int* rowptr = rank + NE2;                     // [NN+1]
    uintptr_t sp = (uintptr_t)(rowptr + NN + 1);
    sp = (sp + 255) & ~(uintptr_t)255;
    int2* sd = (int2*)sp;                         // [NE2] packed (s,d)

    const int* e0 = edges;
    const int* e1 = edges + NE;

    prep_kernel<<<33, 256, 0, stream>>>(Wih_n, Whh_n, bih_n, bhh_n, Wg, bg);
    hipMemsetAsync(deg, 0, (size_t)NN * sizeof(int), stream);
    hist_rank_kernel<<<NE2 / 256, 256, 0, stream>>>(e0, e1, deg, rank);
    scan_kernel<<<1, 1024, 0, stream>>>(deg, rowptr);
    scatter_kernel<<<NE2 / 256, 256, 0, stream>>>(e0, e1, rowptr, rank, sd);
    init_kernel<<<(NN + 255) / 256, 256, 0, stream>>>(classes, W_in, b_in, W1,
                                                      node, u, v, acc);
    for (int it = 0; it < 6; ++it) {
        edge_kernel<<<NE2 / 256, 256, 0, stream>>>(sd, pos, u, v,
                                                   W1, b1, W2, b2, W3, b3, acc);
        node_kernel<<<(NN + 255) / 256, 256, 0, stream>>>(node, acc, Wg, bg, W1,
                                                          u, v, it == 5);
    }
}